// Round 15
// baseline (3723.408 us; speedup 1.0000x reference)
//
#include <hip/hip_runtime.h>
#include <stdint.h>

#define T_STEPS 512

typedef short short8 __attribute__((ext_vector_type(8)));
typedef float floatx4 __attribute__((ext_vector_type(4)));
typedef unsigned int u32x4 __attribute__((ext_vector_type(4)));
typedef unsigned int u32x2 __attribute__((ext_vector_type(2)));

#define MFMA16 __builtin_amdgcn_mfma_f32_16x16x32_bf16

__device__ __forceinline__ unsigned short f2bf(float f) {
  unsigned int u = __builtin_bit_cast(unsigned int, f);
  u = u + 0x7fff + ((u >> 16) & 1);
  return (unsigned short)(u >> 16);
}
__device__ __forceinline__ float bf2f(unsigned short s) {
  unsigned int u = ((unsigned int)s) << 16;
  return __builtin_bit_cast(float, u);
}
__device__ __forceinline__ float sigm(float x) { return 1.f / (1.f + __expf(-x)); }
__device__ __forceinline__ float tanh_fast(float x) {
  float e2 = __expf(2.f * x);
  return 1.f - 2.f / (e2 + 1.f);
}

__device__ __forceinline__ void gload16(const void* g, const void* l) {
  __builtin_amdgcn_global_load_lds((const __attribute__((address_space(1))) unsigned int*)g,
                                   (__attribute__((address_space(3))) unsigned int*)l,
                                   16, 0, 0);
}

// Fire-and-forget tagged-word store (LLC-coherent). u32 = (tag<<16)|bf16.
__device__ __forceinline__ void st_tag(unsigned int* p, unsigned int word) {
  asm volatile("global_store_dword %0, %1, off sc0 sc1" :: "v"(p), "v"(word) : "memory");
}

// ---------------------------------------------------------------------------
// Per-wave-quarter tagged stage with retry BACK-OFF (r15): wave w reads rows
// 0-15 x cols [256w,+256) of the [16][1024] tagged state - 16 instrs, each
// 1KB instruction-contiguous within one row. First attempt immediate (fast
// path = exactly one read when fresh). On stale: s_sleep(12) (~768 cyc)
// before the full re-read - absorbs producer skew in idle time instead of
// hammering the LLC with stale 64KB re-reads (which inflated every block's
// RT). Pack-strip tags, write this wave's Stg quarter (wave-private, no
// barriers). Bounded spin - no hang.
// ---------------------------------------------------------------------------
__device__ __forceinline__ void stage_quarter(const unsigned int* __restrict__ gsrc,
                                              unsigned int target,
                                              unsigned short* Stg, int tid) {
  const int lane = tid & 63, wave = tid >> 6;
  const unsigned int* src = gsrc + wave * 256 + lane * 4;   // row 0, this wave's quarter
  u32x4 w[16];
  int spins = 0;
  for (;;) {
#pragma unroll
    for (int r = 0; r < 16; ++r)
      asm volatile("global_load_dwordx4 %0, %1, off sc0 sc1"
                   : "=v"(w[r]) : "v"(src + r * 1024));
    asm volatile("s_waitcnt vmcnt(0)" ::: "memory");
    __builtin_amdgcn_sched_barrier(0);
    bool ok = true;
#pragma unroll
    for (int r = 0; r < 16; ++r)
#pragma unroll
      for (int q = 0; q < 4; ++q) ok &= ((w[r][q] >> 16) >= target);
    if (__all((int)ok) || ++spins > (1 << 13)) break;   // valve: no hang
    __builtin_amdgcn_s_sleep(12);          // ~768 cyc back-off, then re-read
  }
  // pack (strip tags) and write this wave's Stg quarter.
  const int c16 = wave * 32 + (lane >> 1);
  const int half = lane & 1;
#pragma unroll
  for (int r = 0; r < 16; ++r) {
    u32x2 v;
    v[0] = (w[r][0] & 0xffffu) | (w[r][1] << 16);
    v[1] = (w[r][2] & 0xffffu) | (w[r][3] << 16);
    *(u32x2*)((char*)Stg + r * 2048 + ((c16 ^ (r & 7)) * 16) + half * 8) = v;
  }
  // NO __syncthreads: Stg quarter is wave-private.
}

// ---------------------------------------------------------------------------
__global__ void pack_bf(const float* __restrict__ in, unsigned short* __restrict__ out, int n) {
  int i = blockIdx.x * 256 + threadIdx.x;
  if (i < n) out[i] = f2bf(in[i]);
}

__global__ void packT(const float* __restrict__ src, int srcStride,
                      unsigned short* __restrict__ dst, int dldk, int koff) {
  __shared__ float tile[32][33];
  int tx = threadIdx.x, ty = threadIdx.y;
  int e0 = blockIdx.x * 32, k0 = blockIdx.y * 32;
#pragma unroll
  for (int i = 0; i < 4; ++i)
    tile[ty + 8 * i][tx] = src[(size_t)(k0 + ty + 8 * i) * srcStride + e0 + tx];
  __syncthreads();
#pragma unroll
  for (int i = 0; i < 4; ++i)
    dst[(size_t)(e0 + ty + 8 * i) * dldk + koff + k0 + tx] = f2bf(tile[tx][ty + 8 * i]);
}

__global__ void sentinel(float* out, float v) { out[0] = v; }

// ---------------------------------------------------------------------------
// Big MFMA GEMM (unchanged, verified)
// ---------------------------------------------------------------------------
template <int EPI>
__global__ __launch_bounds__(256) void gemm_bt(
    const unsigned short* __restrict__ A0, const unsigned short* __restrict__ A1,
    const unsigned short* __restrict__ BT,
    int M, int Nn, int K, int KA0,
    const float* __restrict__ bias,
    unsigned short* __restrict__ out_bf,
    const float* __restrict__ xf,
    float* __restrict__ ud,
    unsigned short* __restrict__ rdx,
    float* __restrict__ outf) {
  __shared__ unsigned short At[128 * 32];
  __shared__ unsigned short Bt[128 * 32];
  const int tid = threadIdx.x;
  const int lane = tid & 63, wave = tid >> 6;
  const int wm = wave >> 1, wn = wave & 1;
  const int m0 = blockIdx.y * 128, n0 = blockIdx.x * 128;
  const int lr = lane & 15, lk = (lane >> 4) * 8;
  floatx4 acc[4][4] = {};

  for (int k0 = 0; k0 < K; k0 += 32) {
    const unsigned short* As;
    int kk;
    if (k0 < KA0) { As = A0 + (size_t)m0 * KA0 + k0; kk = KA0; }
    else          { As = A1 + (size_t)m0 * (K - KA0) + (k0 - KA0); kk = K - KA0; }
#pragma unroll
    for (int j = 0; j < 2; ++j) {
      int chunk = j * 256 + tid;
      int row = chunk >> 2, kc = chunk & 3;
      gload16(As + (size_t)row * kk + kc * 8, (const char*)At + chunk * 16);
    }
    const unsigned short* Bs = BT + (size_t)n0 * K + k0;
#pragma unroll
    for (int j = 0; j < 2; ++j) {
      int chunk = j * 256 + tid;
      int row = chunk >> 2, kc = chunk & 3;
      gload16(Bs + (size_t)row * K + kc * 8, (const char*)Bt + chunk * 16);
    }
    __syncthreads();
    short8 a[4], b[4];
#pragma unroll
    for (int i = 0; i < 4; ++i) a[i] = *(const short8*)(At + (wm * 64 + i * 16 + lr) * 32 + lk);
#pragma unroll
    for (int i = 0; i < 4; ++i) b[i] = *(const short8*)(Bt + (wn * 64 + i * 16 + lr) * 32 + lk);
#pragma unroll
    for (int i = 0; i < 4; ++i)
#pragma unroll
      for (int j = 0; j < 4; ++j)
        acc[i][j] = MFMA16(a[i], b[j], acc[i][j], 0, 0, 0);
    __syncthreads();
  }

#pragma unroll
  for (int i = 0; i < 4; ++i) {
#pragma unroll
    for (int j = 0; j < 4; ++j) {
      int col = n0 + wn * 64 + j * 16 + lr;
#pragma unroll
      for (int r = 0; r < 4; ++r) {
        int row = m0 + wm * 64 + i * 16 + (lane >> 4) * 4 + r;
        float v = acc[i][j][r];
        if constexpr (EPI == 0) {
          out_bf[(size_t)row * Nn + col] = f2bf(v + bias[col]);
        } else if constexpr (EPI == 1) {
          float s = sigm(v + bias[col]);
          if (col < 1024) {
            ud[(size_t)row * 1024 + col] = s;
          } else {
            size_t ix = (size_t)row * 1024 + (col - 1024);
            rdx[ix] = f2bf(s * xf[ix]);
          }
        } else {
          float hc = tanh_fast(v + bias[col]);
          size_t ix = (size_t)row * 1024 + col;
          float xv = xf[ix];
          outf[ix] = xv + ud[ix] * (hc - xv);
        }
      }
    }
  }
}

// ---------------------------------------------------------------------------
// Persistent scan (r15 = r14 + retry back-off). Tagged dataflow. 128 blocks =
// 2 groups x 64. Block b owns cols [b*16,b*16+16); thread owns one (row,col).
// Weights Wu/Wr/Wc LDS-resident. Stg wave-private (quarter per wave).
// Per step: stage-h(quarter) -> r-MFMA -> sync -> combine -> store rh ->
// u-MFMA -> sync -> u-combine -> stage-rh(quarter) -> hc-MFMA -> sync ->
// combine -> h update + store -> sync.
// ---------------------------------------------------------------------------
__global__ __launch_bounds__(256, 1) void scan_pk(
    const unsigned short* __restrict__ wgT,   // [2048][1024] u-cols 0-1023, r-cols 1024-2047
    const unsigned short* __restrict__ wcT,   // [1024][1024]
    const unsigned short* __restrict__ gates, // [32*512][3072]
    const float* __restrict__ ph,             // [32][1024]
    unsigned int* __restrict__ hb32,          // [32][1024] tagged h words
    unsigned int* __restrict__ rh32,          // [32][1024] tagged r*h words
    unsigned short* __restrict__ htb,         // [32*512][1024]
    float* __restrict__ lastht)               // [32][1024]
{
  __shared__ unsigned short Wu[16 * 1024];
  __shared__ unsigned short Wr[16 * 1024];
  __shared__ unsigned short Wc[16 * 1024];
  __shared__ unsigned short Stg[16 * 1024];   // packed bf16 state (swizzled, wave-private quarters)
  __shared__ float Part[8][16][17];           // [0..3]=r then hc, [4..7]=u

  const int tid = threadIdx.x;
  const int lane = tid & 63, wave = tid >> 6;
  const int lr = lane & 15, lq = lane >> 4;
  const int g = blockIdx.x >> 6, b = blockIdx.x & 63;
  const int row0 = g * 16, col0 = b * 16;
  const int myrow = tid >> 4, myc = tid & 15;

  // ---- stage weight slices into LDS (source pre-swizzled: chunk ^= row&7) ----
#pragma unroll
  for (int i = 0; i < 8; ++i) {
    int p = i * 256 + tid;                 // 2048 chunks of 16B per array
    int wr = p >> 7, kcp = p & 127;
    int kc = kcp ^ (wr & 7);
    gload16(wgT + (size_t)(col0 + wr) * 1024 + kc * 8,        (const char*)Wu + p * 16);
    gload16(wgT + (size_t)(1024 + col0 + wr) * 1024 + kc * 8, (const char*)Wr + p * 16);
    gload16(wcT + (size_t)(col0 + wr) * 1024 + kc * 8,        (const char*)Wc + p * 16);
  }

  // ---- init: per-thread h element, tag 1 ----
  float Hl = ph[(size_t)(row0 + myrow) * 1024 + col0 + myc];
  st_tag(&hb32[(size_t)(row0 + myrow) * 1024 + col0 + myc], (1u << 16) | f2bf(Hl));
  __syncthreads();                         // weights resident (vmcnt drained)

  const unsigned int* hb32g = hb32 + (size_t)row0 * 1024;
  const unsigned int* rh32g = rh32 + (size_t)row0 * 1024;

  for (int t = 0; t < T_STEPS; ++t) {
    // gate loads (plain cached; issued before the poll so latency overlaps)
    size_t gbase = ((size_t)(row0 + myrow) * T_STEPS + t) * 3072 + col0 + myc;
    unsigned short gU = gates[gbase];
    unsigned short gR = gates[gbase + 1024];
    unsigned short gC = gates[gbase + 2048];

    // ---- stage-poll h(t): this wave's K-quarter only (no barrier) ----
    stage_quarter(hb32g, (unsigned)(t + 1), Stg, tid);

    // ---- r-MFMA: 4-wave K-split, B from Wr ----
    {
      floatx4 aR = {};
#pragma unroll
      for (int ks = 0; ks < 8; ++ks) {
        int sw = ((wave * 8 + ks) * 4 + lq) ^ (lr & 7);
        short8 a = *(const short8*)(Stg + lr * 1024 + sw * 8);
        short8 bR = *(const short8*)(Wr + lr * 1024 + sw * 8);
        aR = MFMA16(a, bR, aR, 0, 0, 0);
      }
#pragma unroll
      for (int r = 0; r < 4; ++r) Part[wave][lq * 4 + r][lr] = aR[r];
    }
    __syncthreads();                       // (1) r-Part ready
    {
      float rpre = Part[0][myrow][myc] + Part[1][myrow][myc] +
                   Part[2][myrow][myc] + Part[3][myrow][myc];
      float rv = sigm(rpre + bf2f(gR));
      st_tag(&rh32[(size_t)(row0 + myrow) * 1024 + col0 + myc],
             ((unsigned)(t + 1) << 16) | f2bf(rv * Hl));   // out early; flight hides under u
    }

    // ---- u-MFMA (independent; Part[4..7] disjoint from r-combine reads) ----
    {
      floatx4 aU = {};
#pragma unroll
      for (int ks = 0; ks < 8; ++ks) {
        int sw = ((wave * 8 + ks) * 4 + lq) ^ (lr & 7);
        short8 a = *(const short8*)(Stg + lr * 1024 + sw * 8);
        short8 bU = *(const short8*)(Wu + lr * 1024 + sw * 8);
        aU = MFMA16(a, bU, aU, 0, 0, 0);
      }
#pragma unroll
      for (int r = 0; r < 4; ++r) Part[4 + wave][lq * 4 + r][lr] = aU[r];
    }
    __syncthreads();                       // (2) u-Part ready (also: all r-combines done)
    float uv;
    {
      float upre = Part[4][myrow][myc] + Part[5][myrow][myc] +
                   Part[6][myrow][myc] + Part[7][myrow][myc];
      uv = sigm(upre + bf2f(gU));
    }

    // ---- stage-poll rh(t): this wave's quarter (no barrier; Stg wave-private) ----
    stage_quarter(rh32g, (unsigned)(t + 1), Stg, tid);

    // ---- hc-MFMA (writes Part[0..3]; all r-combine reads finished at sync 2) ----
    {
      floatx4 c0 = {}, c1 = {};
#pragma unroll
      for (int ks = 0; ks < 8; ks += 2) {
        int sw0 = ((wave * 8 + ks) * 4 + lq) ^ (lr & 7);
        int sw1 = ((wave * 8 + ks + 1) * 4 + lq) ^ (lr & 7);
        short8 a0 = *(const short8*)(Stg + lr * 1024 + sw0 * 8);
        short8 a1 = *(const short8*)(Stg + lr * 1024 + sw1 * 8);
        short8 b0 = *(const short8*)(Wc + lr * 1024 + sw0 * 8);
        short8 b1 = *(const short8*)(Wc + lr * 1024 + sw1 * 8);
        c0 = MFMA16(a0, b0, c0, 0, 0, 0);
        c1 = MFMA16(a1, b1, c1, 0, 0, 0);
      }
#pragma unroll
      for (int r = 0; r < 4; ++r) Part[wave][lq * 4 + r][lr] = c0[r] + c1[r];
    }
    __syncthreads();                       // (3) hc-Part ready
    {
      float cpre = Part[0][myrow][myc] + Part[1][myrow][myc] +
                   Part[2][myrow][myc] + Part[3][myrow][myc];
      float hc = tanh_fast(cpre + bf2f(gC));
      float hn = Hl + uv * (hc - Hl);
      Hl = hn;
      unsigned short hv = f2bf(hn);
      st_tag(&hb32[(size_t)(row0 + myrow) * 1024 + col0 + myc],
             ((unsigned)(t + 2) << 16) | hv);
      htb[((size_t)(row0 + myrow) * T_STEPS + t) * 1024 + col0 + myc] = hv;
      if (t == T_STEPS - 1) lastht[(size_t)(row0 + myrow) * 1024 + col0 + myc] = hn;
    }
    __syncthreads();                       // (4) hc-combine reads done before next r-Part write
  }
}

// ---------------------------------------------------------------------------
extern "C" void kernel_launch(void* const* d_in, const int* in_sizes, int n_in,
                              void* d_out, int out_size, void* d_ws, size_t ws_size,
                              hipStream_t stream) {
  const float* x    = (const float*)d_in[0];   // (32,512,1024)
  const float* ph   = (const float*)d_in[1];   // (32,1024)
  const float* wgt  = (const float*)d_in[2];   // (2048,6144)
  const float* bias = (const float*)d_in[3];   // (6144,)
  float* out = (float*)d_out;                  // h (16777216) + last_ht (32768)

  const size_t SZ_STATE = (size_t)32 * 1024 * 4 * 2;  // hb32 + rh32 (tagged u32)
  const size_t SZ_XBF   = (size_t)16384 * 1024 * 2;
  const size_t SZ_GATES = (size_t)16384 * 3072 * 2;   // rdx aliases here after scan
  const size_t SZ_HTB   = (size_t)16384 * 1024 * 2;
  const size_t SZ_W     = ((size_t)3072 * 1024 + (size_t)2048 * 2048 +
                           (size_t)1024 * 2048 + (size_t)2048 * 1024 +
                           (size_t)1024 * 1024) * 2;
  const size_t REQUIRED = SZ_STATE + SZ_XBF + SZ_GATES + SZ_HTB + SZ_W;

  if (ws_size < REQUIRED) {
    sentinel<<<1, 1, 0, stream>>>(out, (float)ws_size);
    return;
  }

  char* p = (char*)d_ws;
  unsigned int* hb32    = (unsigned int*)p;   p += (size_t)32 * 1024 * 4;
  unsigned int* rh32    = (unsigned int*)p;   p += (size_t)32 * 1024 * 4;
  unsigned short* xbf   = (unsigned short*)p; p += SZ_XBF;
  unsigned short* gates = (unsigned short*)p;
  unsigned short* rdx   = (unsigned short*)p; p += SZ_GATES;
  unsigned short* htb   = (unsigned short*)p; p += SZ_HTB;
  unsigned short* wxtT  = (unsigned short*)p; p += (size_t)3072 * 1024 * 2;
  unsigned short* w1T   = (unsigned short*)p; p += (size_t)2048 * 2048 * 2;
  unsigned short* w2T   = (unsigned short*)p; p += (size_t)1024 * 2048 * 2;
  unsigned short* wgT   = (unsigned short*)p; p += (size_t)2048 * 1024 * 2;
  unsigned short* wcT   = (unsigned short*)p; p += (size_t)1024 * 1024 * 2;
  float* udf = out;  // ud aliases d_out's h region; see gemm epilogues

  // tags must start at 0 each launch (graph replays reuse the buffers)
  hipMemsetAsync(hb32, 0, SZ_STATE, stream);

  dim3 tb(32, 8);
  pack_bf<<<65536, 256, 0, stream>>>(x, xbf, 16384 * 1024);
  packT<<<dim3(96, 32), tb, 0, stream>>>(wgt, 6144, wxtT, 1024, 0);
  packT<<<dim3(64, 64), tb, 0, stream>>>(wgt + 3072, 6144, w1T, 2048, 0);
  packT<<<dim3(32, 32), tb, 0, stream>>>(wgt + (size_t)1024 * 6144 + 5120, 6144, w2T, 2048, 0);
  packT<<<dim3(32, 32), tb, 0, stream>>>(wgt + 5120, 6144, w2T, 2048, 1024);
  packT<<<dim3(64, 32), tb, 0, stream>>>(wgt + (size_t)1024 * 6144, 6144, wgT, 1024, 0);
  packT<<<dim3(32, 32), tb, 0, stream>>>(wgt + (size_t)1024 * 6144 + 2048, 6144, wcT, 1024, 0);

  gemm_bt<0><<<dim3(24, 128), 256, 0, stream>>>(xbf, xbf, wxtT, 16384, 3072, 1024, 1024,
                                                bias, gates, nullptr, nullptr, nullptr, nullptr);

  // persistent recurrence: 128 blocks (proven co-resident), tagged dataflow
  scan_pk<<<128, 256, 0, stream>>>(wgT, wcT, gates, ph, hb32, rh32, htb,
                                   out + (size_t)16384 * 1024);

  gemm_bt<1><<<dim3(16, 128), 256, 0, stream>>>(xbf, htb, w1T, 16384, 2048, 2048, 1024,
                                                bias + 3072, nullptr, x, udf, rdx, nullptr);
  gemm_bt<2><<<dim3(8, 128), 256, 0, stream>>>(htb, rdx, w2T, 16384, 1024, 2048, 1024,
                                               bias + 5120, nullptr, x, udf, nullptr, out);
}

// Round 16
// 3337.804 us; speedup vs baseline: 1.1155x; 1.1155x over previous
//
#include <hip/hip_runtime.h>
#include <stdint.h>

#define T_STEPS 512

typedef short short8 __attribute__((ext_vector_type(8)));
typedef float floatx4 __attribute__((ext_vector_type(4)));
typedef unsigned int u32x4 __attribute__((ext_vector_type(4)));
typedef unsigned int u32x2 __attribute__((ext_vector_type(2)));

#define MFMA16 __builtin_amdgcn_mfma_f32_16x16x32_bf16

__device__ __forceinline__ unsigned short f2bf(float f) {
  unsigned int u = __builtin_bit_cast(unsigned int, f);
  u = u + 0x7fff + ((u >> 16) & 1);
  return (unsigned short)(u >> 16);
}
__device__ __forceinline__ float bf2f(unsigned short s) {
  unsigned int u = ((unsigned int)s) << 16;
  return __builtin_bit_cast(float, u);
}
__device__ __forceinline__ float sigm(float x) { return 1.f / (1.f + __expf(-x)); }
__device__ __forceinline__ float tanh_fast(float x) {
  float e2 = __expf(2.f * x);
  return 1.f - 2.f / (e2 + 1.f);
}

__device__ __forceinline__ void gload16(const void* g, const void* l) {
  __builtin_amdgcn_global_load_lds((const __attribute__((address_space(1))) unsigned int*)g,
                                   (__attribute__((address_space(3))) unsigned int*)l,
                                   16, 0, 0);
}

// Fire-and-forget tagged-word store (LLC-coherent). u32 = (tag<<16)|bf16.
__device__ __forceinline__ void st_tag(unsigned int* p, unsigned int word) {
  asm volatile("global_store_dword %0, %1, off sc0 sc1" :: "v"(p), "v"(word) : "memory");
}

// ---------------------------------------------------------------------------
// Bulk tagged stage (r8-proven, final): read the group's full [16][1024]
// tagged state with instruction-contiguous sc0sc1 loads (1KB/instr/wave),
// retry FULL reads until all tags >= target (every selective/backoff variant
// regressed: r10, r13, r15), strip tags, pack bf16 pairs, write swizzled LDS
// Stg. Ends with __syncthreads. Bounded spin - no hang.
// ---------------------------------------------------------------------------
__device__ __forceinline__ void stage_state(const unsigned int* __restrict__ gsrc,
                                            unsigned int target,
                                            unsigned short* Stg, int tid) {
  const int lane = tid & 63, wave = tid >> 6;
  const unsigned int* src = gsrc + wave * 4096 + lane * 4;
  u32x4 w[16];
  int spins = 0;
  for (;;) {
#pragma unroll
    for (int j = 0; j < 16; ++j)
      asm volatile("global_load_dwordx4 %0, %1, off sc0 sc1"
                   : "=v"(w[j]) : "v"(src + j * 256));
    asm volatile("s_waitcnt vmcnt(0)" ::: "memory");
    __builtin_amdgcn_sched_barrier(0);
    bool ok = true;
#pragma unroll
    for (int j = 0; j < 16; ++j)
#pragma unroll
      for (int q = 0; q < 4; ++q) ok &= ((w[j][q] >> 16) >= target);
    if (__all((int)ok) || ++spins > (1 << 15)) break;   // valve: no hang
    if (spins > 4) __builtin_amdgcn_s_sleep(1);
  }
  // pack (strip tags) and write swizzled LDS: chunk16 c at row r lands at c^(r&7)
  const int half = lane & 1;
  const int chb = lane >> 1;
#pragma unroll
  for (int j = 0; j < 16; ++j) {
    int row = wave * 4 + (j >> 2);
    int c16 = (j & 3) * 32 + chb;
    u32x2 v;
    v[0] = (w[j][0] & 0xffffu) | (w[j][1] << 16);
    v[1] = (w[j][2] & 0xffffu) | (w[j][3] << 16);
    *(u32x2*)((char*)Stg + row * 2048 + ((c16 ^ (row & 7)) * 16) + half * 8) = v;
  }
  __syncthreads();
}

// ---------------------------------------------------------------------------
__global__ void pack_bf(const float* __restrict__ in, unsigned short* __restrict__ out, int n) {
  int i = blockIdx.x * 256 + threadIdx.x;
  if (i < n) out[i] = f2bf(in[i]);
}

__global__ void packT(const float* __restrict__ src, int srcStride,
                      unsigned short* __restrict__ dst, int dldk, int koff) {
  __shared__ float tile[32][33];
  int tx = threadIdx.x, ty = threadIdx.y;
  int e0 = blockIdx.x * 32, k0 = blockIdx.y * 32;
#pragma unroll
  for (int i = 0; i < 4; ++i)
    tile[ty + 8 * i][tx] = src[(size_t)(k0 + ty + 8 * i) * srcStride + e0 + tx];
  __syncthreads();
#pragma unroll
  for (int i = 0; i < 4; ++i)
    dst[(size_t)(e0 + ty + 8 * i) * dldk + koff + k0 + tx] = f2bf(tile[tx][ty + 8 * i]);
}

__global__ void sentinel(float* out, float v) { out[0] = v; }

// ---------------------------------------------------------------------------
// Big MFMA GEMM (verified): C = epilogue([A0|A1] @ BT^T + bias), BT is N x K.
// Tile 128x128, BK=32, global_load_lds width-16 staging, 4 waves, 4x4 frags.
// ---------------------------------------------------------------------------
template <int EPI>
__global__ __launch_bounds__(256) void gemm_bt(
    const unsigned short* __restrict__ A0, const unsigned short* __restrict__ A1,
    const unsigned short* __restrict__ BT,
    int M, int Nn, int K, int KA0,
    const float* __restrict__ bias,
    unsigned short* __restrict__ out_bf,
    const float* __restrict__ xf,
    float* __restrict__ ud,
    unsigned short* __restrict__ rdx,
    float* __restrict__ outf) {
  __shared__ unsigned short At[128 * 32];
  __shared__ unsigned short Bt[128 * 32];
  const int tid = threadIdx.x;
  const int lane = tid & 63, wave = tid >> 6;
  const int wm = wave >> 1, wn = wave & 1;
  const int m0 = blockIdx.y * 128, n0 = blockIdx.x * 128;
  const int lr = lane & 15, lk = (lane >> 4) * 8;
  floatx4 acc[4][4] = {};

  for (int k0 = 0; k0 < K; k0 += 32) {
    const unsigned short* As;
    int kk;
    if (k0 < KA0) { As = A0 + (size_t)m0 * KA0 + k0; kk = KA0; }
    else          { As = A1 + (size_t)m0 * (K - KA0) + (k0 - KA0); kk = K - KA0; }
#pragma unroll
    for (int j = 0; j < 2; ++j) {
      int chunk = j * 256 + tid;
      int row = chunk >> 2, kc = chunk & 3;
      gload16(As + (size_t)row * kk + kc * 8, (const char*)At + chunk * 16);
    }
    const unsigned short* Bs = BT + (size_t)n0 * K + k0;
#pragma unroll
    for (int j = 0; j < 2; ++j) {
      int chunk = j * 256 + tid;
      int row = chunk >> 2, kc = chunk & 3;
      gload16(Bs + (size_t)row * K + kc * 8, (const char*)Bt + chunk * 16);
    }
    __syncthreads();
    short8 a[4], b[4];
#pragma unroll
    for (int i = 0; i < 4; ++i) a[i] = *(const short8*)(At + (wm * 64 + i * 16 + lr) * 32 + lk);
#pragma unroll
    for (int i = 0; i < 4; ++i) b[i] = *(const short8*)(Bt + (wn * 64 + i * 16 + lr) * 32 + lk);
#pragma unroll
    for (int i = 0; i < 4; ++i)
#pragma unroll
      for (int j = 0; j < 4; ++j)
        acc[i][j] = MFMA16(a[i], b[j], acc[i][j], 0, 0, 0);
    __syncthreads();
  }

#pragma unroll
  for (int i = 0; i < 4; ++i) {
#pragma unroll
    for (int j = 0; j < 4; ++j) {
      int col = n0 + wn * 64 + j * 16 + lr;
#pragma unroll
      for (int r = 0; r < 4; ++r) {
        int row = m0 + wm * 64 + i * 16 + (lane >> 4) * 4 + r;
        float v = acc[i][j][r];
        if constexpr (EPI == 0) {
          out_bf[(size_t)row * Nn + col] = f2bf(v + bias[col]);
        } else if constexpr (EPI == 1) {
          float s = sigm(v + bias[col]);
          if (col < 1024) {
            ud[(size_t)row * 1024 + col] = s;
          } else {
            size_t ix = (size_t)row * 1024 + (col - 1024);
            rdx[ix] = f2bf(s * xf[ix]);
          }
        } else {
          float hc = tanh_fast(v + bias[col]);
          size_t ix = (size_t)row * 1024 + col;
          float xv = xf[ix];
          outf[ix] = xv + ud[ix] * (hc - xv);   // ud aliases outf at same ix: safe
        }
      }
    }
  }
}

// ---------------------------------------------------------------------------
// Persistent scan (final = r8). Tagged dataflow: state words u32=(tag<<16)|bf16,
// fire-and-forget producer stores, consumer bulk-reads + full retry. No flags,
// no drains, no barriers between blocks, no cache invalidation (gates/weights
// stay cached). 128 blocks = 2 groups x 64. Block b owns cols [b*16,b*16+16);
// thread owns one (row,col). Weights Wu/Wr/Wc LDS-resident (XOR-swizzled).
// Per step: stage-poll h -> r-MFMA -> combine -> store rh(tag t+1) -> u-MFMA
// -> combine (hides rh flight) -> stage-poll rh -> hc-MFMA -> combine ->
// h update -> store h(tag t+2).
// Structural floor: 512 steps x 2 dependent LLC round-trip exchanges.
// ---------------------------------------------------------------------------
__global__ __launch_bounds__(256, 1) void scan_pk(
    const unsigned short* __restrict__ wgT,   // [2048][1024] u-cols 0-1023, r-cols 1024-2047
    const unsigned short* __restrict__ wcT,   // [1024][1024]
    const unsigned short* __restrict__ gates, // [32*512][3072]
    const float* __restrict__ ph,             // [32][1024]
    unsigned int* __restrict__ hb32,          // [32][1024] tagged h words
    unsigned int* __restrict__ rh32,          // [32][1024] tagged r*h words
    unsigned short* __restrict__ htb,         // [32*512][1024]
    float* __restrict__ lastht)               // [32][1024]
{
  __shared__ unsigned short Wu[16 * 1024];
  __shared__ unsigned short Wr[16 * 1024];
  __shared__ unsigned short Wc[16 * 1024];
  __shared__ unsigned short Stg[16 * 1024];   // packed bf16 state (swizzled)
  __shared__ float Part[8][16][17];           // [0..3]=r then hc, [4..7]=u

  const int tid = threadIdx.x;
  const int lane = tid & 63, wave = tid >> 6;
  const int lr = lane & 15, lq = lane >> 4;
  const int g = blockIdx.x >> 6, b = blockIdx.x & 63;
  const int row0 = g * 16, col0 = b * 16;
  const int myrow = tid >> 4, myc = tid & 15;

  // ---- stage weight slices into LDS (source pre-swizzled: chunk ^= row&7) ----
#pragma unroll
  for (int i = 0; i < 8; ++i) {
    int p = i * 256 + tid;                 // 2048 chunks of 16B per array
    int wr = p >> 7, kcp = p & 127;
    int kc = kcp ^ (wr & 7);
    gload16(wgT + (size_t)(col0 + wr) * 1024 + kc * 8,        (const char*)Wu + p * 16);
    gload16(wgT + (size_t)(1024 + col0 + wr) * 1024 + kc * 8, (const char*)Wr + p * 16);
    gload16(wcT + (size_t)(col0 + wr) * 1024 + kc * 8,        (const char*)Wc + p * 16);
  }

  // ---- init: per-thread h element, tag 1 ----
  float Hl = ph[(size_t)(row0 + myrow) * 1024 + col0 + myc];
  st_tag(&hb32[(size_t)(row0 + myrow) * 1024 + col0 + myc], (1u << 16) | f2bf(Hl));
  __syncthreads();                         // weights resident (vmcnt drained)

  const unsigned int* hb32g = hb32 + (size_t)row0 * 1024;
  const unsigned int* rh32g = rh32 + (size_t)row0 * 1024;

  for (int t = 0; t < T_STEPS; ++t) {
    // gate loads (plain cached; issued before the poll so latency overlaps)
    size_t gbase = ((size_t)(row0 + myrow) * T_STEPS + t) * 3072 + col0 + myc;
    unsigned short gU = gates[gbase];
    unsigned short gR = gates[gbase + 1024];
    unsigned short gC = gates[gbase + 2048];

    // ---- stage-poll h(t) into Stg ----
    stage_state(hb32g, (unsigned)(t + 1), Stg, tid);

    // ---- r-MFMA: 4-wave K-split, B from Wr ----
    {
      floatx4 aR = {};
#pragma unroll
      for (int ks = 0; ks < 8; ++ks) {
        int sw = ((wave * 8 + ks) * 4 + lq) ^ (lr & 7);
        short8 a = *(const short8*)(Stg + lr * 1024 + sw * 8);
        short8 bR = *(const short8*)(Wr + lr * 1024 + sw * 8);
        aR = MFMA16(a, bR, aR, 0, 0, 0);
      }
#pragma unroll
      for (int r = 0; r < 4; ++r) Part[wave][lq * 4 + r][lr] = aR[r];
    }
    __syncthreads();
    {
      float rpre = Part[0][myrow][myc] + Part[1][myrow][myc] +
                   Part[2][myrow][myc] + Part[3][myrow][myc];
      float rv = sigm(rpre + bf2f(gR));
      st_tag(&rh32[(size_t)(row0 + myrow) * 1024 + col0 + myc],
             ((unsigned)(t + 1) << 16) | f2bf(rv * Hl));   // out early; flight hides under u
    }

    // ---- u-MFMA (independent; Part[4..7] disjoint from r-combine reads) ----
    {
      floatx4 aU = {};
#pragma unroll
      for (int ks = 0; ks < 8; ++ks) {
        int sw = ((wave * 8 + ks) * 4 + lq) ^ (lr & 7);
        short8 a = *(const short8*)(Stg + lr * 1024 + sw * 8);
        short8 bU = *(const short8*)(Wu + lr * 1024 + sw * 8);
        aU = MFMA16(a, bU, aU, 0, 0, 0);
      }
#pragma unroll
      for (int r = 0; r < 4; ++r) Part[4 + wave][lq * 4 + r][lr] = aU[r];
    }
    __syncthreads();
    float uv;
    {
      float upre = Part[4][myrow][myc] + Part[5][myrow][myc] +
                   Part[6][myrow][myc] + Part[7][myrow][myc];
      uv = sigm(upre + bf2f(gU));
    }

    // ---- stage-poll rh(t) into Stg (overwrites h; u-MFMA done per syncs) ----
    stage_state(rh32g, (unsigned)(t + 1), Stg, tid);

    // ---- hc-MFMA ----
    {
      floatx4 c0 = {}, c1 = {};
#pragma unroll
      for (int ks = 0; ks < 8; ks += 2) {
        int sw0 = ((wave * 8 + ks) * 4 + lq) ^ (lr & 7);
        int sw1 = ((wave * 8 + ks + 1) * 4 + lq) ^ (lr & 7);
        short8 a0 = *(const short8*)(Stg + lr * 1024 + sw0 * 8);
        short8 a1 = *(const short8*)(Stg + lr * 1024 + sw1 * 8);
        short8 b0 = *(const short8*)(Wc + lr * 1024 + sw0 * 8);
        short8 b1 = *(const short8*)(Wc + lr * 1024 + sw1 * 8);
        c0 = MFMA16(a0, b0, c0, 0, 0, 0);
        c1 = MFMA16(a1, b1, c1, 0, 0, 0);
      }
#pragma unroll
      for (int r = 0; r < 4; ++r) Part[wave][lq * 4 + r][lr] = c0[r] + c1[r];
    }
    __syncthreads();
    {
      float cpre = Part[0][myrow][myc] + Part[1][myrow][myc] +
                   Part[2][myrow][myc] + Part[3][myrow][myc];
      float hc = tanh_fast(cpre + bf2f(gC));
      float hn = Hl + uv * (hc - Hl);
      Hl = hn;
      unsigned short hv = f2bf(hn);
      st_tag(&hb32[(size_t)(row0 + myrow) * 1024 + col0 + myc],
             ((unsigned)(t + 2) << 16) | hv);
      htb[((size_t)(row0 + myrow) * T_STEPS + t) * 1024 + col0 + myc] = hv;
      if (t == T_STEPS - 1) lastht[(size_t)(row0 + myrow) * 1024 + col0 + myc] = hn;
    }
  }
}

// ---------------------------------------------------------------------------
extern "C" void kernel_launch(void* const* d_in, const int* in_sizes, int n_in,
                              void* d_out, int out_size, void* d_ws, size_t ws_size,
                              hipStream_t stream) {
  const float* x    = (const float*)d_in[0];   // (32,512,1024)
  const float* ph   = (const float*)d_in[1];   // (32,1024)
  const float* wgt  = (const float*)d_in[2];   // (2048,6144)
  const float* bias = (const float*)d_in[3];   // (6144,)
  float* out = (float*)d_out;                  // h (16777216) + last_ht (32768)

  const size_t SZ_STATE = (size_t)32 * 1024 * 4 * 2;  // hb32 + rh32 (tagged u32)
  const size_t SZ_XBF   = (size_t)16384 * 1024 * 2;
  const size_t SZ_GATES = (size_t)16384 * 3072 * 2;   // rdx aliases here after scan
  const size_t SZ_HTB   = (size_t)16384 * 1024 * 2;
  const size_t SZ_W     = ((size_t)3072 * 1024 + (size_t)2048 * 2048 +
                           (size_t)1024 * 2048 + (size_t)2048 * 1024 +
                           (size_t)1024 * 1024) * 2;
  const size_t REQUIRED = SZ_STATE + SZ_XBF + SZ_GATES + SZ_HTB + SZ_W;

  if (ws_size < REQUIRED) {
    sentinel<<<1, 1, 0, stream>>>(out, (float)ws_size);
    return;
  }

  char* p = (char*)d_ws;
  unsigned int* hb32    = (unsigned int*)p;   p += (size_t)32 * 1024 * 4;
  unsigned int* rh32    = (unsigned int*)p;   p += (size_t)32 * 1024 * 4;
  unsigned short* xbf   = (unsigned short*)p; p += SZ_XBF;
  unsigned short* gates = (unsigned short*)p;
  unsigned short* rdx   = (unsigned short*)p; p += SZ_GATES;
  unsigned short* htb   = (unsigned short*)p; p += SZ_HTB;
  unsigned short* wxtT  = (unsigned short*)p; p += (size_t)3072 * 1024 * 2;
  unsigned short* w1T   = (unsigned short*)p; p += (size_t)2048 * 2048 * 2;
  unsigned short* w2T   = (unsigned short*)p; p += (size_t)1024 * 2048 * 2;
  unsigned short* wgT   = (unsigned short*)p; p += (size_t)2048 * 1024 * 2;
  unsigned short* wcT   = (unsigned short*)p; p += (size_t)1024 * 1024 * 2;
  float* udf = out;  // ud aliases d_out's h region; see gemm epilogues

  // tags must start at 0 each launch (graph replays reuse the buffers)
  hipMemsetAsync(hb32, 0, SZ_STATE, stream);

  dim3 tb(32, 8);
  pack_bf<<<65536, 256, 0, stream>>>(x, xbf, 16384 * 1024);
  packT<<<dim3(96, 32), tb, 0, stream>>>(wgt, 6144, wxtT, 1024, 0);
  packT<<<dim3(64, 64), tb, 0, stream>>>(wgt + 3072, 6144, w1T, 2048, 0);
  packT<<<dim3(32, 32), tb, 0, stream>>>(wgt + (size_t)1024 * 6144 + 5120, 6144, w2T, 2048, 0);
  packT<<<dim3(32, 32), tb, 0, stream>>>(wgt + 5120, 6144, w2T, 2048, 1024);
  packT<<<dim3(64, 32), tb, 0, stream>>>(wgt + (size_t)1024 * 6144, 6144, wgT, 1024, 0);
  packT<<<dim3(32, 32), tb, 0, stream>>>(wgt + (size_t)1024 * 6144 + 2048, 6144, wcT, 1024, 0);

  // gates = bf16(x @ Wxt + bt)
  gemm_bt<0><<<dim3(24, 128), 256, 0, stream>>>(xbf, xbf, wxtT, 16384, 3072, 1024, 1024,
                                                bias, gates, nullptr, nullptr, nullptr, nullptr);

  // persistent recurrence: 128 blocks (proven co-resident), tagged dataflow
  scan_pk<<<128, 256, 0, stream>>>(wgT, wcT, gates, ph, hb32, rh32, htb,
                                   out + (size_t)16384 * 1024);

  // grd = sigmoid(bd[:2048] + [x|ht] @ W1T^T) -> ud (f32, in d_out), rdx = bf16(rd*x)
  gemm_bt<1><<<dim3(16, 128), 256, 0, stream>>>(xbf, htb, w1T, 16384, 2048, 2048, 1024,
                                                bias + 3072, nullptr, x, udf, rdx, nullptr);
  // h = x + ud*(tanh(bd[2048:] + [ht|rdx] @ W2T^T) - x)
  gemm_bt<2><<<dim3(8, 128), 256, 0, stream>>>(htb, rdx, w2T, 16384, 1024, 2048, 1024,
                                               bias + 5120, nullptr, x, udf, nullptr, out);
}